// Round 10
// baseline (1225.189 us; speedup 1.0000x reference)
//
#include <hip/hip_runtime.h>

typedef unsigned short u16;
typedef unsigned int   u32;

static __device__ __forceinline__ float sigf (float x){ return 1.0f/(1.0f+__expf(-x)); }
static __device__ __forceinline__ float tanh_(float x){ return 2.0f/(1.0f+__expf(-2.0f*x)) - 1.0f; }

// sizes
#define NM 2730            // 273*10 distinct (t, j=b%10) rows
#define N_O0 878080        // 245*128*28
#define N_O3 978432        // 273*128*28
#define NWIN 133770        // NM*49

static __device__ __forceinline__ int dot4(u32 a, u32 b, int acc){
#if __has_builtin(__builtin_amdgcn_sdot4)
  return __builtin_amdgcn_sdot4((int)a, (int)b, acc, false);
#else
  int s = acc;
  #pragma unroll
  for(int i=0;i<4;i++){
    int av = (int)((signed char)((a >> (8*i)) & 0xffu));
    int bv = (int)((signed char)((b >> (8*i)) & 0xffu));
    s += av*bv;
  }
  return s;
#endif
}

// ---- fused prep: xT + 6 transposes + Whh row scales ----
// segments (items): xT 38400 | wih0 50176 | wih1/2/3 262144 ea | linW 65536
// | scW 7168 | scales 4096.  total 951808 -> 3718 blocks
__global__ __launch_bounds__(256) void k_prep(
    const float* __restrict__ x,     float* __restrict__ xT,
    const float* __restrict__ wi0,   float* __restrict__ wT0,
    const float* __restrict__ wi1,   float* __restrict__ wT1,
    const float* __restrict__ wi2,   float* __restrict__ wT2,
    const float* __restrict__ wi3,   float* __restrict__ wT3,
    const float* __restrict__ lw,    float* __restrict__ lwT,
    const float* __restrict__ sw,    float* __restrict__ swT,
    const float* __restrict__ h0, const float* __restrict__ h1,
    const float* __restrict__ h2, const float* __restrict__ h3,
    float* __restrict__ zsc){
  int i = blockIdx.x*256 + threadIdx.x;
  if(i < 38400){                    // xT
    int t = i >> 7, b = i & 127;
    xT[i] = x[b*300 + t];
    return;
  }
  i -= 38400;
  if(i < 50176){ int c=i/1024, r=i-c*1024; wT0[i] = wi0[r*49 + c];  return; }
  i -= 50176;
  if(i < 262144){ int c=i>>10, r=i&1023; wT1[i] = wi1[r*256 + c];   return; }
  i -= 262144;
  if(i < 262144){ int c=i>>10, r=i&1023; wT2[i] = wi2[r*256 + c];   return; }
  i -= 262144;
  if(i < 262144){ int c=i>>10, r=i&1023; wT3[i] = wi3[r*256 + c];   return; }
  i -= 262144;
  if(i < 65536){ int c=i>>8, r=i&255; lwT[i] = lw[r*256 + c];       return; }
  i -= 65536;
  if(i < 7168){ int c=i/28, r=i-c*28; swT[i] = sw[r*256 + c];       return; }
  i -= 7168;
  if(i < 4096){                     // per-row absmax scale
    int l = i >> 10, r = i & 1023;
    const float* W = (l==0)?h0:(l==1)?h1:(l==2)?h2:h3;
    const float4* p = (const float4*)(W + (size_t)r*256);
    float m = 0.f;
    #pragma unroll 8
    for(int q=0;q<64;q++){
      float4 v = p[q];
      m = fmaxf(m, fmaxf(fmaxf(fabsf(v.x),fabsf(v.y)), fmaxf(fabsf(v.z),fabsf(v.w))));
    }
    zsc[i] = fmaxf(m, 1e-20f) * (1.0f/889.0f);   // rowmax/(7*127)
  }
}

// ---- fused int4 pack + ES scan ----
// blocks 0..511: pack 131072 u32 (4 layers x 32768); block 512: ES scan.
// pack layout (per layer): u32 uidx = (((js*8+rr)*2+q)*128 + kg)*4 + dw
//   row = rr*128+kg ; k = js*64 + q*32 + dw*8 + {pairs}
//   byte b: lo nibble = n(k+2b), hi = n(k+2b+1), n = wq+8, wq in [-7,7]
__global__ __launch_bounds__(256) void k_packes(
    const float* __restrict__ h0, const float* __restrict__ h1,
    const float* __restrict__ h2, const float* __restrict__ h3,
    const float* __restrict__ zsc, u32* __restrict__ W4,
    const float* __restrict__ xT, const float* __restrict__ alpha,
    const float* __restrict__ gamma, const float* __restrict__ iseas,
    float* __restrict__ ST, float* __restrict__ lvlT){
  if(blockIdx.x < 512){
    int i = blockIdx.x*256 + threadIdx.x;      // 0..131071
    int l = i >> 15;
    int uidx = i & 32767;
    int dw = uidx & 3;
    int t2 = uidx >> 2;
    int kg = t2 & 127;
    int t3 = t2 >> 7;
    int q  = t3 & 1;
    int t4 = t3 >> 1;
    int rr = t4 & 7;
    int js = t4 >> 3;
    int row = rr*128 + kg;
    int k0  = js*64 + q*32 + dw*8;
    const float* W = (l==0)?h0:(l==1)?h1:(l==2)?h2:h3;
    float inv = 1.0f / (zsc[l*1024 + row] * 127.0f);   // 7/rowmax
    u32 out = 0;
    #pragma unroll
    for(int b=0;b<4;b++){
      float we = W[(size_t)row*256 + k0 + 2*b];
      float wo = W[(size_t)row*256 + k0 + 2*b + 1];
      int ne = max(-7, min(7, __float2int_rn(we*inv))) + 8;
      int no = max(-7, min(7, __float2int_rn(wo*inv))) + 8;
      out |= ((u32)(ne | (no<<4))) << (8*b);
    }
    W4[i] = out;
    return;
  }
  // ES scan (block 512, threads 0..127)
  int b = threadIdx.x;
  if(b >= 128) return;
  float a = sigf(alpha[b]);
  float g = sigf(gamma[b]);
  float S0[7];
  #pragma unroll
  for(int i=0;i<7;i++){ S0[i] = __expf(iseas[b*7+i]); ST[i*128+b] = S0[i]; }
  ST[7*128+b] = S0[0];
  float q0=S0[1],q1=S0[2],q2=S0[3],q3=S0[4],q4=S0[5],q5=S0[6],q6=S0[0];
  float lvl = xT[b]/S0[0];
  lvlT[b] = lvl;
  for(int t=1;t<300;t++){
    float xt = xT[t*128+b];
    float s  = q0;
    lvl = a*(xt/s) + (1.0f-a)*lvl;
    float sn = g*(xt/lvl) + (1.0f-g)*s;
    q0=q1;q1=q2;q2=q3;q3=q4;q4=q5;q5=q6;q6=sn;
    lvlT[t*128+b]   = lvl;
    ST[(t+7)*128+b] = sn;
  }
}

// ---- fused window_input + actual_values + hav/hav_norm ----
__global__ __launch_bounds__(256) void k_winwout(
    const float* __restrict__ xT, const float* __restrict__ ST,
    const float* __restrict__ lvlT, const float* __restrict__ cats,
    const float* __restrict__ mp, const float* __restrict__ val,
    float* __restrict__ win, float* __restrict__ out){
  int i = blockIdx.x*256 + threadIdx.x;
  if(i < NWIN){
    int f = i % 49;
    int m = i / 49;
    int j = m % 10, t = m / 10;
    float v;
    if(f < 28){
      int c = t + f;
      v = xT[c*128 + j] / ST[c*128 + j] / lvlT[(t+27)*128 + j];
    } else if(f < 48){
      v = cats[j*20 + (f-28)];
    } else {
      v = mp[0];
    }
    win[i] = v;
    return;
  }
  i -= NWIN;
  if(i < N_O0){
    int o = i % 28;
    int b = (i/28) % 128;
    int t = i/(28*128);
    int c = 28 + t + o;
    out[878080 + i] = xT[c*128+b] / ST[c*128+b] / lvlT[(27+t)*128+b];
    return;
  }
  i -= N_O0;
  if(i < 3584){
    int b = i/28, o = i%28;
    int col = (o < 21) ? (286+o) : (279+o);
    float Sm = ST[col*128 + b];
    float lv = lvlT[299*128 + b];
    out[2738176 + i] = val[i];             // hav
    out[2741760 + i] = val[i] / Sm / lv;   // hav_norm
  }
}

// ---- batched xz = X @ WihT + b : block = 8 rows x 1024 gates ----
__global__ __launch_bounds__(256) void k_gemm(const float* __restrict__ X,
                                              const float* __restrict__ WT,   // [F][1024] f32
                                              const float* __restrict__ bias, // [1024] f32
                                              float* __restrict__ Z, int F){
  __shared__ float Xs[8][256];
  const int tid = threadIdx.x;
  const int m0 = blockIdx.x*8;
  for(int p=0;p<8;p++){
    int m = m0+p;
    for(int f=tid; f<F; f+=256)
      Xs[p][f] = (m < NM) ? X[m*F+f] : 0.0f;
  }
  __syncthreads();
  float acc0[8], acc1[8], acc2[8], acc3[8];
  {
    float b0 = bias[tid];
    float b1 = bias[tid+256];
    float b2 = bias[tid+512];
    float b3 = bias[tid+768];
    #pragma unroll
    for(int p=0;p<8;p++){ acc0[p]=b0; acc1[p]=b1; acc2[p]=b2; acc3[p]=b3; }
  }
  #pragma unroll 4
  for(int f=0; f<F; f++){
    float w0 = WT[f*1024 + tid      ];
    float w1 = WT[f*1024 + tid+256  ];
    float w2 = WT[f*1024 + tid+512  ];
    float w3 = WT[f*1024 + tid+768  ];
    #pragma unroll
    for(int p=0;p<8;p++){
      float xv = Xs[p][f];
      acc0[p] += w0*xv; acc1[p] += w1*xv; acc2[p] += w2*xv; acc3[p] += w3*xv;
    }
  }
  for(int p=0;p<8;p++){
    int m = m0+p;
    if(m < NM){
      float* zb = Z + m*1024 + tid;
      zb[0]=acc0[p]; zb[256]=acc1[p]; zb[512]=acc2[p]; zb[768]=acc3[p];
    }
  }
}

// ---- LSTM scan v7: one WG (512 thr) per chain; int4 Whh (excess-8
// nibbles) streamed, sdot4 on 0..15 bytes + exact -8*sum(h) correction;
// h int8 (scale 127). Thread (kg=tid&127, js=tid>>7): k-slice js*64..+64,
// rows {kg, kg+128, ..., kg+896}. 128 KB/step stream.
__global__ __launch_bounds__(512) void k_scan7(
    const float* __restrict__ Z,
    const u32* __restrict__ W4,    // packed int4 weights (128 KB)
    const float* __restrict__ zsc, // [1024] per-row z scales
    float* __restrict__ Y,
    const float* __restrict__ RES,
    int d){
  __shared__ __align__(16) u32 h8E[32];  // even-k int8 h (byte i = h[2i])
  __shared__ __align__(16) u32 h8O[32];  // odd-k
  __shared__ int   SH[4];                // per-js-slice sum of h int8
  __shared__ int   zp[4][1024];
  __shared__ float sc[1024];
  const int tid = threadIdx.x;
  const int chain = blockIdx.x;
  const int j = chain % 10;
  const int r = chain / 10;
  const int ns = (273 - r + d - 1)/d;
  const int kg = tid & 127;
  const int js = tid >> 7;
  const uint4* Wb = (const uint4*)W4 + (size_t)js*2048 + kg;
  const uint4* hE4 = (const uint4*)h8E + js*2;
  const uint4* hO4 = (const uint4*)h8O + js*2;
  const u32 M = 0x0F0F0F0Fu;

  for(int i=tid;i<1024;i+=512) sc[i] = zsc[i];
  if(tid < 32) h8E[tid] = 0u;
  else if(tid < 64) h8O[tid-32] = 0u;
  if(tid < 4) SH[tid] = 0;
  float cst = 0.0f;
  __syncthreads();

  int t = r;
  for(int s=0; s<ns; s++, t+=d){
    uint4 hE0 = hE4[0], hE1 = hE4[1];
    uint4 hO0 = hO4[0], hO1 = hO4[1];
    const int corr = 8 * SH[js];
    #pragma unroll
    for(int rr=0;rr<8;rr++){
      int acc = -corr;
      uint4 w0 = Wb[(rr*2  )*128];
      acc = dot4(w0.x & M, hE0.x, acc); acc = dot4((w0.x>>4) & M, hO0.x, acc);
      acc = dot4(w0.y & M, hE0.y, acc); acc = dot4((w0.y>>4) & M, hO0.y, acc);
      acc = dot4(w0.z & M, hE0.z, acc); acc = dot4((w0.z>>4) & M, hO0.z, acc);
      acc = dot4(w0.w & M, hE0.w, acc); acc = dot4((w0.w>>4) & M, hO0.w, acc);
      uint4 w1 = Wb[(rr*2+1)*128];
      acc = dot4(w1.x & M, hE1.x, acc); acc = dot4((w1.x>>4) & M, hO1.x, acc);
      acc = dot4(w1.y & M, hE1.y, acc); acc = dot4((w1.y>>4) & M, hO1.y, acc);
      acc = dot4(w1.z & M, hE1.z, acc); acc = dot4((w1.z>>4) & M, hO1.z, acc);
      acc = dot4(w1.w & M, hE1.w, acc); acc = dot4((w1.w>>4) & M, hO1.w, acc);
      zp[js][rr*128 + kg] = acc;
    }
    __syncthreads();
    if(tid < 256){
      const int u = tid;
      const float* zb = Z + (size_t)(t*10 + j)*1024;
      int si = zp[0][u]     + zp[1][u]     + zp[2][u]     + zp[3][u];
      int sf = zp[0][u+256] + zp[1][u+256] + zp[2][u+256] + zp[3][u+256];
      int sg = zp[0][u+512] + zp[1][u+512] + zp[2][u+512] + zp[3][u+512];
      int so = zp[0][u+768] + zp[1][u+768] + zp[2][u+768] + zp[3][u+768];
      float zi = zb[u]     + sc[u]     * (float)si;
      float zf = zb[u+256] + sc[u+256] * (float)sf;
      float zg = zb[u+512] + sc[u+512] * (float)sg;
      float zo = zb[u+768] + sc[u+768] * (float)so;
      float c  = sigf(zf)*cst + sigf(zi)*tanh_(zg);
      float h  = sigf(zo)*tanh_(c);
      cst = c;
      int hqi = __float2int_rn(h * 127.0f);
      hqi = max(-127, min(127, hqi));
      if(u & 1) ((signed char*)h8O)[u>>1] = (signed char)hqi;
      else      ((signed char*)h8E)[u>>1] = (signed char)hqi;
      int hs = hqi;
      hs += __shfl_xor(hs, 1);
      hs += __shfl_xor(hs, 2);
      hs += __shfl_xor(hs, 4);
      hs += __shfl_xor(hs, 8);
      hs += __shfl_xor(hs, 16);
      hs += __shfl_xor(hs, 32);
      if((tid & 63) == 0) SH[tid>>6] = hs;
      float o = h;
      if(RES) o += RES[(size_t)(t*10+j)*256 + u];
      Y[(size_t)(t*10+j)*256 + u] = o;
    }
    __syncthreads();
  }
}

// ---- fused head + outputs: h=tanh(Y4@linW.T+lb); rnn=h@scW.T+sb;
// broadcast by b%10 into o0/o3; holdout (t==272) into o2 ----
__global__ __launch_bounds__(256) void k_headout(const float* __restrict__ Y4,
    const float* __restrict__ LWT,  // [256][256] f32 (linWT [f][u])
    const float* __restrict__ lb,
    const float* __restrict__ SWT,  // [256][28] f32  (scoreT [f][o])
    const float* __restrict__ sb,
    const float* __restrict__ ST, const float* __restrict__ lvlT,
    float* __restrict__ out){
  __shared__ float v [8][256];
  __shared__ float h2[8][256];
  const int tid = threadIdx.x;
  const int m0 = blockIdx.x*8;
  for(int p=0;p<8;p++){
    int m = m0+p;
    v[p][tid] = (m<NM) ? Y4[m*256+tid] : 0.0f;
  }
  __syncthreads();
  float acc[8];
  float bz = lb[tid];
  #pragma unroll
  for(int p=0;p<8;p++) acc[p]=bz;
  #pragma unroll 4
  for(int f=0; f<256; f++){
    float w = LWT[f*256+tid];
    #pragma unroll
    for(int p=0;p<8;p++) acc[p] += w * v[p][f];
  }
  #pragma unroll
  for(int p=0;p<8;p++) h2[p][tid] = tanh_(acc[p]);
  __syncthreads();
  if(tid < 224){
    int o = tid % 28, p = tid / 28;
    int m = m0 + p;
    if(m < NM){
      float a = sb[o];
      for(int f=0; f<256; f++) a += SWT[f*28+o] * h2[p][f];
      int t = m / 10, j = m - t*10;
      float* o0 = out;                 // prediction_values (245,128,28)
      float* o3 = out + 1759744;       // rnn_out (273,128,28)
      for(int b=j; b<128; b+=10){
        size_t idx = (size_t)t*3584 + b*28 + o;
        o3[idx] = a;
        if(t < 245) o0[idx] = a;
      }
      if(t == 272){
        int col = (o < 21) ? (286+o) : (279+o);
        float* o2 = out + 1756160;     // holdout_prediction (128,28)
        for(int b=j; b<128; b+=10){
          float hv = a * ST[col*128 + b] * lvlT[299*128 + b];
          o2[b*28 + o] = (hv > 0.0f) ? hv : 0.0f;
        }
      }
    }
  }
}

extern "C" void kernel_launch(void* const* d_in, const int* in_sizes, int n_in,
                              void* d_out, int out_size, void* d_ws, size_t ws_size,
                              hipStream_t stream){
  (void)in_sizes; (void)n_in; (void)out_size; (void)ws_size;
  const float* x     = (const float*)d_in[0];
  const float* val   = (const float*)d_in[1];
  const float* alpha = (const float*)d_in[2];
  const float* gamma = (const float*)d_in[3];
  const float* iseas = (const float*)d_in[4];
  const float* cats  = (const float*)d_in[5];
  const float* mp    = (const float*)d_in[6];
  const float* Wih[4]  = {(const float*)d_in[7],  (const float*)d_in[10], (const float*)d_in[13], (const float*)d_in[16]};
  const float* Whh[4]  = {(const float*)d_in[8],  (const float*)d_in[11], (const float*)d_in[14], (const float*)d_in[17]};
  const float* bias[4] = {(const float*)d_in[9],  (const float*)d_in[12], (const float*)d_in[15], (const float*)d_in[18]};
  const float* linW  = (const float*)d_in[19];
  const float* linb  = (const float*)d_in[20];
  const float* scW   = (const float*)d_in[21];
  const float* scb   = (const float*)d_in[22];

  // ---- workspace layout: f32 region, then u32 packed-int4 region ----
  float* Fw   = (float*)d_ws;
  float* ST   = Fw;                 // 39296
  float* lvlT = ST   + 39296;       // 38400
  float* xT   = lvlT + 38400;       // 38400
  float* win  = xT   + 38400;       // 133776
  float* xz   = win  + 133776;      // 2795520
  float* yA   = xz   + 2795520;     // 698880  (L1 out / L3 out / L4 out)
  float* yB   = yA   + 698880;      // 698880  (L2 out, residual)
  float* wihT[4];
  wihT[0] = yB + 698880;            // 50176
  wihT[1] = wihT[0] + 50176;        // 262144
  wihT[2] = wihT[1] + 262144;
  wihT[3] = wihT[2] + 262144;
  float* linWT = wihT[3] + 262144;  // 65536
  float* scT   = linWT + 65536;     // 7168
  float* zsc   = scT   + 7168;      // 4096 (4 layers x 1024)
  u32*   W4all = (u32*)(zsc + 4096);// 4 x 32768 u32 = 512 KB

  // ---- prep: xT + transposes + row scales (1 launch) ----
  k_prep<<<3718, 256, 0, stream>>>(x, xT,
      Wih[0], wihT[0], Wih[1], wihT[1], Wih[2], wihT[2], Wih[3], wihT[3],
      linW, linWT, scW, scT,
      Whh[0], Whh[1], Whh[2], Whh[3], zsc);

  // ---- int4 pack (blocks 0..511) + ES scan (block 512) ----
  k_packes<<<513, 256, 0, stream>>>(Whh[0], Whh[1], Whh[2], Whh[3], zsc, W4all,
                                    xT, alpha, gamma, iseas, ST, lvlT);

  // ---- windows + actual_values + hav/hav_norm ----
  k_winwout<<<(NWIN + N_O0 + 3584 + 255)/256, 256, 0, stream>>>(
      xT, ST, lvlT, cats, mp, val, win, (float*)d_out);

  // ---- 4 LSTM layers: batched Wih GEMM + int4-dot4 stream scan ----
  const int    dlt[4]    = {1, 2, 2, 6};
  const int    chains[4] = {10, 20, 20, 60};
  const float* Xin[4]    = {win, yA, yB, yA};
  float*       Yout[4]   = {yA, yB, yA, yA};
  const int    Fdim[4]   = {49, 256, 256, 256};
  for(int l=0;l<4;l++){
    k_gemm<<<(NM+7)/8, 256, 0, stream>>>(Xin[l], wihT[l], bias[l], xz, Fdim[l]);
    k_scan7<<<chains[l], 512, 0, stream>>>(xz, W4all + l*32768, zsc + l*1024,
                                           Yout[l],
                                           (l==3) ? yB : (const float*)nullptr, dlt[l]);
  }

  // ---- fused head + outputs ----
  k_headout<<<(NM+7)/8, 256, 0, stream>>>(yA, linWT, linb, scT, scb,
                                          ST, lvlT, (float*)d_out);
}

// Round 11
// 1034.768 us; speedup vs baseline: 1.1840x; 1.1840x over previous
//
#include <hip/hip_runtime.h>

typedef unsigned short u16;
typedef unsigned int   u32;

static __device__ __forceinline__ float sigf (float x){ return 1.0f/(1.0f+__expf(-x)); }
static __device__ __forceinline__ float tanh_(float x){ return 2.0f/(1.0f+__expf(-2.0f*x)) - 1.0f; }

// sizes
#define NM 2730            // 273*10 distinct (t, j=b%10) rows
#define N_O0 878080        // 245*128*28
#define N_O3 978432        // 273*128*28

static __device__ __forceinline__ int dot4(u32 a, u32 b, int acc){
#if __has_builtin(__builtin_amdgcn_sdot4)
  return __builtin_amdgcn_sdot4((int)a, (int)b, acc, false);
#else
  int s = acc;
  #pragma unroll
  for(int i=0;i<4;i++){
    int av = (int)((signed char)((a >> (8*i)) & 0xffu));
    int bv = (int)((signed char)((b >> (8*i)) & 0xffu));
    s += av*bv;
  }
  return s;
#endif
}

// ---- fused prep: xT + 6 transposes + Whh row scales ----
// items: xT 38400 | wih0 50176 | wih1/2/3 262144 ea | linW 65536 | scW 7168
// | scales 4096 -> 951808 -> 3718 blocks
__global__ __launch_bounds__(256) void k_prep(
    const float* __restrict__ x,     float* __restrict__ xT,
    const float* __restrict__ wi0,   float* __restrict__ wT0,
    const float* __restrict__ wi1,   float* __restrict__ wT1,
    const float* __restrict__ wi2,   float* __restrict__ wT2,
    const float* __restrict__ wi3,   float* __restrict__ wT3,
    const float* __restrict__ lw,    float* __restrict__ lwT,
    const float* __restrict__ sw,    float* __restrict__ swT,
    const float* __restrict__ h0, const float* __restrict__ h1,
    const float* __restrict__ h2, const float* __restrict__ h3,
    float* __restrict__ zsc){
  int i = blockIdx.x*256 + threadIdx.x;
  if(i < 38400){                    // xT
    int t = i >> 7, b = i & 127;
    xT[i] = x[b*300 + t];
    return;
  }
  i -= 38400;
  if(i < 50176){ int c=i/1024, r=i-c*1024; wT0[i] = wi0[r*49 + c];  return; }
  i -= 50176;
  if(i < 262144){ int c=i>>10, r=i&1023; wT1[i] = wi1[r*256 + c];   return; }
  i -= 262144;
  if(i < 262144){ int c=i>>10, r=i&1023; wT2[i] = wi2[r*256 + c];   return; }
  i -= 262144;
  if(i < 262144){ int c=i>>10, r=i&1023; wT3[i] = wi3[r*256 + c];   return; }
  i -= 262144;
  if(i < 65536){ int c=i>>8, r=i&255; lwT[i] = lw[r*256 + c];       return; }
  i -= 65536;
  if(i < 7168){ int c=i/28, r=i-c*28; swT[i] = sw[r*256 + c];       return; }
  i -= 7168;
  if(i < 4096){                     // per-row absmax scale (int8)
    int l = i >> 10, r = i & 1023;
    const float* W = (l==0)?h0:(l==1)?h1:(l==2)?h2:h3;
    const float4* p = (const float4*)(W + (size_t)r*256);
    float m = 0.f;
    #pragma unroll 8
    for(int q=0;q<64;q++){
      float4 v = p[q];
      m = fmaxf(m, fmaxf(fmaxf(fabsf(v.x),fabsf(v.y)), fmaxf(fabsf(v.z),fabsf(v.w))));
    }
    zsc[i] = fmaxf(m, 1e-20f) * (1.0f/16129.0f);   // rowmax/(127*127)
  }
}

// ---- fused int8 pack + ES scan ----
// blocks 0..1023: pack 262144 u32 (4 layers x 65536); block 1024: ES scan.
// per-layer u32 idx uidx: dw=uidx&3, kg=(uidx>>2)&127, q=(uidx>>9)&3,
// rr=(uidx>>11)&7, js=uidx>>14 ; row=rr*128+kg ; k0=js*64+q*16+dw*4
__global__ __launch_bounds__(256) void k_packes(
    const float* __restrict__ h0, const float* __restrict__ h1,
    const float* __restrict__ h2, const float* __restrict__ h3,
    const float* __restrict__ zsc, u32* __restrict__ W8,
    const float* __restrict__ xT, const float* __restrict__ alpha,
    const float* __restrict__ gamma, const float* __restrict__ iseas,
    float* __restrict__ ST, float* __restrict__ lvlT){
  if(blockIdx.x < 1024){
    int i = blockIdx.x*256 + threadIdx.x;      // 0..262143
    int l = i >> 16;
    int uidx = i & 65535;
    int dw = uidx & 3;
    int kg = (uidx >> 2) & 127;
    int q  = (uidx >> 9) & 3;
    int rr = (uidx >> 11) & 7;
    int js = uidx >> 14;
    int row = rr*128 + kg;
    int k0  = js*64 + q*16 + dw*4;
    const float* W = (l==0)?h0:(l==1)?h1:(l==2)?h2:h3;
    float inv = 1.0f / (zsc[l*1024 + row] * 127.0f);
    u32 out = 0;
    #pragma unroll
    for(int b=0;b<4;b++){
      float v = W[(size_t)row*256 + k0 + b];
      int q8 = max(-127, min(127, __float2int_rn(v * inv)));
      out |= ((u32)(q8 & 0xff)) << (8*b);
    }
    W8[i] = out;
    return;
  }
  // ES scan (block 1024, threads 0..127)
  int b = threadIdx.x;
  if(b >= 128) return;
  float a = sigf(alpha[b]);
  float g = sigf(gamma[b]);
  float S0[7];
  #pragma unroll
  for(int i=0;i<7;i++){ S0[i] = __expf(iseas[b*7+i]); ST[i*128+b] = S0[i]; }
  ST[7*128+b] = S0[0];
  float q0=S0[1],q1=S0[2],q2=S0[3],q3=S0[4],q4=S0[5],q5=S0[6],q6=S0[0];
  float lvl = xT[b]/S0[0];
  lvlT[b] = lvl;
  for(int t=1;t<300;t++){
    float xt = xT[t*128+b];
    float s  = q0;
    lvl = a*(xt/s) + (1.0f-a)*lvl;
    float sn = g*(xt/lvl) + (1.0f-g)*s;
    q0=q1;q1=q2;q2=q3;q3=q4;q4=q5;q5=q6;q6=sn;
    lvlT[t*128+b]   = lvl;
    ST[(t+7)*128+b] = sn;
  }
}

// ---- gemm for layer 1: window_input built on the fly in staging ----
__global__ __launch_bounds__(256) void k_gemm1(
    const float* __restrict__ xT, const float* __restrict__ ST,
    const float* __restrict__ lvlT, const float* __restrict__ cats,
    const float* __restrict__ mp,
    const float* __restrict__ WT,   // [49][1024] f32
    const float* __restrict__ bias, // [1024] f32
    float* __restrict__ Z){
  __shared__ float Xs[8][52];
  const int tid = threadIdx.x;
  const int m0 = blockIdx.x*8;
  for(int idx=tid; idx<8*49; idx+=256){
    int p = idx/49, f = idx - p*49;
    int m = m0+p;
    float v = 0.f;
    if(m < NM){
      int tt = m/10, jj = m - (m/10)*10;
      if(f < 28){
        int c = tt + f;
        v = xT[c*128 + jj] / ST[c*128 + jj] / lvlT[(tt+27)*128 + jj];
      } else if(f < 48){
        v = cats[jj*20 + (f-28)];
      } else {
        v = mp[0];
      }
    }
    Xs[p][f] = v;
  }
  __syncthreads();
  float acc0[8], acc1[8], acc2[8], acc3[8];
  {
    float b0 = bias[tid];
    float b1 = bias[tid+256];
    float b2 = bias[tid+512];
    float b3 = bias[tid+768];
    #pragma unroll
    for(int p=0;p<8;p++){ acc0[p]=b0; acc1[p]=b1; acc2[p]=b2; acc3[p]=b3; }
  }
  #pragma unroll 7
  for(int f=0; f<49; f++){
    float w0 = WT[f*1024 + tid      ];
    float w1 = WT[f*1024 + tid+256  ];
    float w2 = WT[f*1024 + tid+512  ];
    float w3 = WT[f*1024 + tid+768  ];
    #pragma unroll
    for(int p=0;p<8;p++){
      float xv = Xs[p][f];
      acc0[p] += w0*xv; acc1[p] += w1*xv; acc2[p] += w2*xv; acc3[p] += w3*xv;
    }
  }
  for(int p=0;p<8;p++){
    int m = m0+p;
    if(m < NM){
      float* zb = Z + m*1024 + tid;
      zb[0]=acc0[p]; zb[256]=acc1[p]; zb[512]=acc2[p]; zb[768]=acc3[p];
    }
  }
}

// ---- batched xz = X @ WihT + b (F=256 layers) ----
__global__ __launch_bounds__(256) void k_gemm(const float* __restrict__ X,
                                              const float* __restrict__ WT,   // [256][1024] f32
                                              const float* __restrict__ bias, // [1024] f32
                                              float* __restrict__ Z){
  __shared__ float Xs[8][256];
  const int tid = threadIdx.x;
  const int m0 = blockIdx.x*8;
  for(int p=0;p<8;p++){
    int m = m0+p;
    Xs[p][tid] = (m < NM) ? X[m*256+tid] : 0.0f;
  }
  __syncthreads();
  float acc0[8], acc1[8], acc2[8], acc3[8];
  {
    float b0 = bias[tid];
    float b1 = bias[tid+256];
    float b2 = bias[tid+512];
    float b3 = bias[tid+768];
    #pragma unroll
    for(int p=0;p<8;p++){ acc0[p]=b0; acc1[p]=b1; acc2[p]=b2; acc3[p]=b3; }
  }
  #pragma unroll 4
  for(int f=0; f<256; f++){
    float w0 = WT[f*1024 + tid      ];
    float w1 = WT[f*1024 + tid+256  ];
    float w2 = WT[f*1024 + tid+512  ];
    float w3 = WT[f*1024 + tid+768  ];
    #pragma unroll
    for(int p=0;p<8;p++){
      float xv = Xs[p][f];
      acc0[p] += w0*xv; acc1[p] += w1*xv; acc2[p] += w2*xv; acc3[p] += w3*xv;
    }
  }
  for(int p=0;p<8;p++){
    int m = m0+p;
    if(m < NM){
      float* zb = Z + m*1024 + tid;
      zb[0]=acc0[p]; zb[256]=acc1[p]; zb[512]=acc2[p]; zb[768]=acc3[p];
    }
  }
}

// ---- LSTM scan v8: int8 sdot4 stream (R9 structure) + 40KB LDS weight
// slice (q=0, rr=0..4) + Z/RES prefetch. One WG (512 thr) per chain.
// Thread (kg=tid&127, js=tid>>7): k-slice js*64..+64, rows {kg,kg+128,...}.
// 216 KB/step streamed from L2 + 40 KB from LDS.
__global__ __launch_bounds__(512) void k_scan8(
    const float* __restrict__ Z,
    const u32* __restrict__ W8,    // packed int8 weights (256 KB)
    const float* __restrict__ zsc, // [1024] per-row z scales
    float* __restrict__ Y,
    const float* __restrict__ RES,
    int d){
  __shared__ __align__(16) u32 h8[64];   // 256 int8 h
  __shared__ int   zp[4][1024];          // 16 KB partials
  __shared__ float sc[1024];             // 4 KB row scales
  __shared__ __align__(16) u32 wl[5*2048];  // 40 KB LDS weight slice
  const int tid = threadIdx.x;
  const int chain = blockIdx.x;
  const int j = chain % 10;
  const int r = chain / 10;
  const int ns = (273 - r + d - 1)/d;
  const int kg = tid & 127;
  const int js = tid >> 7;
  const uint4* Wb = (const uint4*)W8 + (size_t)js*4096 + kg;
  const uint4* hq = (const uint4*)h8 + js*4;
  uint4* wl4 = (uint4*)wl;

  for(int i=tid;i<1024;i+=512) sc[i] = zsc[i];
  #pragma unroll
  for(int rr=0;rr<5;rr++) wl4[rr*512 + tid] = Wb[rr*512];   // q=0 slice
  if(tid < 64) h8[tid] = 0u;
  float cst = 0.0f;
  __syncthreads();

  int t = r;
  for(int s=0; s<ns; s++, t+=d){
    const size_t row = (size_t)(t*10 + j);
    float zv0=0.f, zv1=0.f, zv2=0.f, zv3=0.f, rv=0.f;
    if(tid < 256){                       // prefetch (consumed after barrier)
      const float* zb = Z + row*1024;
      zv0 = zb[tid]; zv1 = zb[tid+256]; zv2 = zb[tid+512]; zv3 = zb[tid+768];
      if(RES) rv = RES[row*256 + tid];
    }
    int a0=0,a1=0,a2=0,a3=0,a4=0,a5=0,a6=0,a7=0;
    #pragma unroll
    for(int q=0;q<4;q++){
      uint4 h4 = hq[q];                  // broadcast: 16 h int8
      #pragma unroll
      for(int rr=0;rr<8;rr++){
        uint4 w = (q==0 && rr<5) ? wl4[rr*512 + tid] : Wb[rr*512 + q*128];
        int* ap = (rr==0)?&a0:(rr==1)?&a1:(rr==2)?&a2:(rr==3)?&a3:
                  (rr==4)?&a4:(rr==5)?&a5:(rr==6)?&a6:&a7;
        int acc = *ap;
        acc = dot4(w.x, h4.x, acc);
        acc = dot4(w.y, h4.y, acc);
        acc = dot4(w.z, h4.z, acc);
        acc = dot4(w.w, h4.w, acc);
        *ap = acc;
      }
    }
    zp[js][       kg] = a0;
    zp[js][128  + kg] = a1;
    zp[js][256  + kg] = a2;
    zp[js][384  + kg] = a3;
    zp[js][512  + kg] = a4;
    zp[js][640  + kg] = a5;
    zp[js][768  + kg] = a6;
    zp[js][896  + kg] = a7;
    __syncthreads();
    if(tid < 256){
      const int u = tid;
      int si = zp[0][u]     + zp[1][u]     + zp[2][u]     + zp[3][u];
      int sf = zp[0][u+256] + zp[1][u+256] + zp[2][u+256] + zp[3][u+256];
      int sg = zp[0][u+512] + zp[1][u+512] + zp[2][u+512] + zp[3][u+512];
      int so = zp[0][u+768] + zp[1][u+768] + zp[2][u+768] + zp[3][u+768];
      float zi = zv0 + sc[u]     * (float)si;
      float zf = zv1 + sc[u+256] * (float)sf;
      float zg = zv2 + sc[u+512] * (float)sg;
      float zo = zv3 + sc[u+768] * (float)so;
      float c  = sigf(zf)*cst + sigf(zi)*tanh_(zg);
      float h  = sigf(zo)*tanh_(c);
      cst = c;
      int hqi = __float2int_rn(h * 127.0f);
      hqi = max(-127, min(127, hqi));
      ((signed char*)h8)[u] = (signed char)hqi;
      Y[row*256 + u] = h + rv;
    }
    __syncthreads();
  }
}

// ---- fused head + all remaining outputs ----
// blocks 0..341: h=tanh(Y4@linW.T+lb); rnn=h@scW.T+sb; broadcast into
// o0/o3; holdout (t==272) into o2. blocks 342..: actual_values + hav.
__global__ __launch_bounds__(256) void k_headout(const float* __restrict__ Y4,
    const float* __restrict__ LWT,  // [256][256] f32 (linWT [f][u])
    const float* __restrict__ lb,
    const float* __restrict__ SWT,  // [256][28] f32  (scoreT [f][o])
    const float* __restrict__ sb,
    const float* __restrict__ ST, const float* __restrict__ lvlT,
    const float* __restrict__ xT, const float* __restrict__ val,
    float* __restrict__ out){
  __shared__ float v [8][256];
  __shared__ float h2[8][256];
  const int tid = threadIdx.x;
  if(blockIdx.x >= 342){
    int i = (blockIdx.x - 342)*256 + tid;
    if(i < N_O0){                        // actual_values
      int o = i % 28;
      int b = (i/28) % 128;
      int t = i/(28*128);
      int c = 28 + t + o;
      out[878080 + i] = xT[c*128+b] / ST[c*128+b] / lvlT[(27+t)*128+b];
    } else {
      i -= N_O0;
      if(i < 3584){                      // hav + hav_norm
        int b = i/28, o = i%28;
        int col = (o < 21) ? (286+o) : (279+o);
        float Sm = ST[col*128 + b];
        float lv = lvlT[299*128 + b];
        out[2738176 + i] = val[i];
        out[2741760 + i] = val[i] / Sm / lv;
      }
    }
    return;
  }
  const int m0 = blockIdx.x*8;
  for(int p=0;p<8;p++){
    int m = m0+p;
    v[p][tid] = (m<NM) ? Y4[m*256+tid] : 0.0f;
  }
  __syncthreads();
  float acc[8];
  float bz = lb[tid];
  #pragma unroll
  for(int p=0;p<8;p++) acc[p]=bz;
  #pragma unroll 4
  for(int f=0; f<256; f++){
    float w = LWT[f*256+tid];
    #pragma unroll
    for(int p=0;p<8;p++) acc[p] += w * v[p][f];
  }
  #pragma unroll
  for(int p=0;p<8;p++) h2[p][tid] = tanh_(acc[p]);
  __syncthreads();
  if(tid < 224){
    int o = tid % 28, p = tid / 28;
    int m = m0 + p;
    if(m < NM){
      float a = sb[o];
      for(int f=0; f<256; f++) a += SWT[f*28+o] * h2[p][f];
      int t = m / 10, j = m - t*10;
      float* o0 = out;                 // prediction_values (245,128,28)
      float* o3 = out + 1759744;       // rnn_out (273,128,28)
      for(int b=j; b<128; b+=10){
        size_t idx = (size_t)t*3584 + b*28 + o;
        o3[idx] = a;
        if(t < 245) o0[idx] = a;
      }
      if(t == 272){
        int col = (o < 21) ? (286+o) : (279+o);
        float* o2 = out + 1756160;     // holdout_prediction (128,28)
        for(int b=j; b<128; b+=10){
          float hv = a * ST[col*128 + b] * lvlT[299*128 + b];
          o2[b*28 + o] = (hv > 0.0f) ? hv : 0.0f;
        }
      }
    }
  }
}

extern "C" void kernel_launch(void* const* d_in, const int* in_sizes, int n_in,
                              void* d_out, int out_size, void* d_ws, size_t ws_size,
                              hipStream_t stream){
  (void)in_sizes; (void)n_in; (void)out_size; (void)ws_size;
  const float* x     = (const float*)d_in[0];
  const float* val   = (const float*)d_in[1];
  const float* alpha = (const float*)d_in[2];
  const float* gamma = (const float*)d_in[3];
  const float* iseas = (const float*)d_in[4];
  const float* cats  = (const float*)d_in[5];
  const float* mp    = (const float*)d_in[6];
  const float* Wih[4]  = {(const float*)d_in[7],  (const float*)d_in[10], (const float*)d_in[13], (const float*)d_in[16]};
  const float* Whh[4]  = {(const float*)d_in[8],  (const float*)d_in[11], (const float*)d_in[14], (const float*)d_in[17]};
  const float* bias[4] = {(const float*)d_in[9],  (const float*)d_in[12], (const float*)d_in[15], (const float*)d_in[18]};
  const float* linW  = (const float*)d_in[19];
  const float* linb  = (const float*)d_in[20];
  const float* scW   = (const float*)d_in[21];
  const float* scb   = (const float*)d_in[22];

  // ---- workspace layout: f32 region, then u32 packed-int8 region ----
  float* Fw   = (float*)d_ws;
  float* ST   = Fw;                 // 39296
  float* lvlT = ST   + 39296;       // 38400
  float* xT   = lvlT + 38400;       // 38400
  float* xz   = xT   + 38400;       // 2795520
  float* yA   = xz   + 2795520;     // 698880  (L1 out / L3 out / L4 out)
  float* yB   = yA   + 698880;      // 698880  (L2 out, residual)
  float* wihT[4];
  wihT[0] = yB + 698880;            // 50176
  wihT[1] = wihT[0] + 50176;        // 262144
  wihT[2] = wihT[1] + 262144;
  wihT[3] = wihT[2] + 262144;
  float* linWT = wihT[3] + 262144;  // 65536
  float* scT   = linWT + 65536;     // 7168
  float* zsc   = scT   + 7168;      // 4096 (4 layers x 1024)
  u32*   W8all = (u32*)(zsc + 4096);// 4 x 65536 u32 = 1 MB

  // ---- prep: xT + transposes + row scales (1 launch) ----
  k_prep<<<3718, 256, 0, stream>>>(x, xT,
      Wih[0], wihT[0], Wih[1], wihT[1], Wih[2], wihT[2], Wih[3], wihT[3],
      linW, linWT, scW, scT,
      Whh[0], Whh[1], Whh[2], Whh[3], zsc);

  // ---- int8 pack (blocks 0..1023) + ES scan (block 1024) ----
  k_packes<<<1025, 256, 0, stream>>>(Whh[0], Whh[1], Whh[2], Whh[3], zsc, W8all,
                                     xT, alpha, gamma, iseas, ST, lvlT);

  // ---- 4 LSTM layers: Wih GEMM (win folded into L1) + int8 scan ----
  const int    dlt[4]    = {1, 2, 2, 6};
  const int    chains[4] = {10, 20, 20, 60};
  const float* Xin[4]    = {nullptr, yA, yB, yA};
  float*       Yout[4]   = {yA, yB, yA, yA};
  for(int l=0;l<4;l++){
    if(l == 0)
      k_gemm1<<<(NM+7)/8, 256, 0, stream>>>(xT, ST, lvlT, cats, mp,
                                            wihT[0], bias[0], xz);
    else
      k_gemm<<<(NM+7)/8, 256, 0, stream>>>(Xin[l], wihT[l], bias[l], xz);
    k_scan8<<<chains[l], 512, 0, stream>>>(xz, W8all + l*65536, zsc + l*1024,
                                           Yout[l],
                                           (l==3) ? yB : (const float*)nullptr, dlt[l]);
  }

  // ---- fused head + outputs (+ actual_values + hav) ----
  k_headout<<<342 + (N_O0 + 3584 + 255)/256, 256, 0, stream>>>(
      yA, linWT, linb, scT, scb, ST, lvlT, xT, val, (float*)d_out);
}